// Round 5
// baseline (16275.888 us; speedup 1.0000x reference)
//
#include <hip/hip_runtime.h>
#include <cmath>

constexpr int kB = 64, kS = 512, kD = 128, kH = 512, kOut = 24;
constexpr int kBlocks = 256, kThreads = 1024;  // 1024 thr: 16 waves/CU (4/SIMD)
constexpr size_t kBarOffBytes = (size_t)5 * kB * kH * 4;   // after H0,H1,tmp1

struct Params {
  const float* x;
  const float* w0[4]; const float* b0[4];   // f,i,o,g  [512,640] / [512]
  const float* w1[4]; const float* b1[4];   // f,i,o,g  [512,1024] / [512]
  const float* fc1w; const float* fc1b;
  const float* fc2w; const float* fc2b;
  float* H0;    // 2 buffers [64][512]
  float* H1;    // 2 buffers [64][512]
  float* tmp1;  // [64][512]
  unsigned* bar; // word layout: dom slots [0,4096), dom gen @4096+d*16,
                 //              full slots [4224,8320), full gen @8320
  float* out;   // [64][24]
};

__device__ __forceinline__ float sigmoidf_(float v) {
  return 1.0f / (1.0f + expf(-v));
}

// Store-based group barrier (parallel slot stores, no RMW serialization).
// Leader polls all n slots with n lanes + __syncthreads_and. Monotone.
__device__ __forceinline__ void sync_group(unsigned* slots, unsigned* gen,
                                           int myIdx, int n, bool leader,
                                           unsigned r) {
  const int tid = threadIdx.x;
  __syncthreads();
  if (leader) {
    if (tid == 0) {
      __threadfence();
      __hip_atomic_store(slots + myIdx * 16, r + 1, __ATOMIC_RELAXED,
                         __HIP_MEMORY_SCOPE_AGENT);
    }
    unsigned* ps = slots + (tid < n ? tid : 0) * 16;
    for (;;) {
      unsigned v = __hip_atomic_load(ps, __ATOMIC_RELAXED,
                                     __HIP_MEMORY_SCOPE_AGENT);
      if (__syncthreads_and((tid < n) ? (int)(v > r) : 1)) break;
      __builtin_amdgcn_s_sleep(1);
    }
    __threadfence();
    if (tid == 0)
      __hip_atomic_store(gen, r + 1, __ATOMIC_RELAXED,
                         __HIP_MEMORY_SCOPE_AGENT);
    __syncthreads();
  } else {
    if (tid == 0) {
      __threadfence();
      __hip_atomic_store(slots + myIdx * 16, r + 1, __ATOMIC_RELAXED,
                         __HIP_MEMORY_SCOPE_AGENT);
      while (__hip_atomic_load(gen, __ATOMIC_RELAXED,
                               __HIP_MEMORY_SCOPE_AGENT) <= r)
        __builtin_amdgcn_s_sleep(1);
      __threadfence();
    }
    __syncthreads();
  }
}

// Block (cgi, bh): cgi=bid>>1 owns hidden cols j0=4*cgi..+3, bh=bid&1 owns
// batches bh*32..+31 (same tile as round 4; round-4 verified).
// NEW: 1024 threads over the same tile -> 4 waves/SIMD (was 2) to hide
// ds_read latency; per-CU LDS/FMA totals conserved.
// Thread tid = r4*256 + kt*8 + bg:
//   bits 0-2 bg (batch grp), 3-7 kt (32-way k-split; 3-5 = ktlow in-wave,
//   6-7 = kthigh = wave&3), 8-9 r4 (gate). k-split reduction: butterfly
//   __shfl_xor over lane bits 3/4/5 (free of LDS), then 4-way via 8KB LDS.
__global__ void __launch_bounds__(kThreads, 4)
lstm_persistent(Params p) {
  __shared__ float wlds0[16 * 640];    // 40 KB  w0 slice
  __shared__ float wlds1[16 * 1024];   // 64 KB  w1 slice
  __shared__ float ustg[2][32 * 132];  // 33.8 KB dbuf u-stage (part unions in)
  __shared__ float gs[512];            // gate preacts [row(16)][b(32)]

  const int tid = threadIdx.x;
  const int bid = blockIdx.x;
  const int cgi = bid >> 1;
  const int bh  = bid & 1;
  const int j0  = cgi * 4;
  const int bbase = bh * 32;

  const int r4 = tid >> 8;
  const int kt = (tid >> 3) & 31;
  const int bg = tid & 7;
  const int lane = tid & 63;
  const int kh = (tid >> 6) & 3;       // kthigh = wave&3

  // staging map: each thread stages exactly ONE float4 per chunk
  const int k4s = tid & 31;
  const int bbs = tid >> 5;            // 0..31
  const int bL  = bbase + bbs;

  unsigned rnd = 0;

  // one-time: weight slice -> LDS
  for (int idx = tid; idx < 16 * 160; idx += kThreads) {   // w0: 16 x 160 f4
    const int row = idx / 160;
    const int k4  = idx - row * 160;
    const float4 v =
        *(const float4*)(p.w0[row >> 2] + (j0 + (row & 3)) * 640 + k4 * 4);
    *(float4*)(wlds0 + row * 640 + k4 * 4) = v;
  }
  for (int idx = tid; idx < 16 * 256; idx += kThreads) {   // w1: 16 x 256 f4
    const int row = idx >> 8;
    const int k4  = idx & 255;
    const float4 v =
        *(const float4*)(p.w1[row >> 2] + (j0 + (row & 3)) * 1024 + k4 * 4);
    *(float4*)(wlds1 + row * 1024 + k4 * 4) = v;
  }

  // zero-init buffers read at t=0 (buffer index 1)
  if (tid < 128) {
    const int jl = tid >> 5, bb = tid & 31;
    const int b = bbase + bb;
    p.H0[kB * kH + b * kH + j0 + jl] = 0.f;
    p.H1[kB * kH + b * kH + j0 + jl] = 0.f;
  }

  float* H0buf[2] = { p.H0, p.H0 + kB * kH };
  float* H1buf[2] = { p.H1, p.H1 + kB * kH };
  float c0 = 0.f, c1 = 0.f;

  unsigned* domSlots = p.bar + bh * 2048;
  unsigned* domGen   = p.bar + 4096 + bh * 16;
  const bool leader  = (cgi == 0);

  sync_group(domSlots, domGen, cgi, 128, leader, rnd); rnd++;

  // Phase: C chunks of 128 k. Weights from LDS (broadcast, conflict-free);
  // u dbuf-staged; per chunk each thread covers ONE k4 slot (its kt).
  auto runPhase = [&](int C, auto&& src, const float* __restrict__ wl,
                      int wstride, const float* const* Bv, float& cs,
                      float* __restrict__ hout) {
    float acc[4][4];
    #pragma unroll
    for (int a = 0; a < 4; ++a)
      #pragma unroll
      for (int q = 0; q < 4; ++q) acc[a][q] = 0.f;

    const float* wr[4];
    #pragma unroll
    for (int rr = 0; rr < 4; ++rr) wr[rr] = wl + (r4 * 4 + rr) * wstride;

    auto compute = [&](int c, const float* __restrict__ ub0) {
      float4 wv[4], uv[4];
      #pragma unroll
      for (int rr = 0; rr < 4; ++rr)
        wv[rr] = *(const float4*)(wr[rr] + c * 128 + kt * 4);  // LDS bcast
      #pragma unroll
      for (int i2 = 0; i2 < 4; ++i2)
        uv[i2] = *(const float4*)(ub0 + (bg + 8 * i2) * 132 + kt * 4);
      #pragma unroll
      for (int rr = 0; rr < 4; ++rr)
        #pragma unroll
        for (int i2 = 0; i2 < 4; ++i2) {
          acc[rr][i2] = fmaf(wv[rr].x, uv[i2].x, acc[rr][i2]);
          acc[rr][i2] = fmaf(wv[rr].y, uv[i2].y, acc[rr][i2]);
          acc[rr][i2] = fmaf(wv[rr].z, uv[i2].z, acc[rr][i2]);
          acc[rr][i2] = fmaf(wv[rr].w, uv[i2].w, acc[rr][i2]);
        }
    };

    // set A = even chunks, set B = odd chunks (static names, no spills)
    float4 sA, sB;
    sA = *(const float4*)src(0, bL, k4s);
    if (C > 1) sB = *(const float4*)src(1, bL, k4s);
    *(float4*)(&ustg[0][bbs * 132 + k4s * 4]) = sA;
    __syncthreads();

    for (int cc = 0; cc < C; cc += 2) {
      { // even chunk c = cc in ustg[0]
        const int c = cc;
        if (c + 2 < C) sA = *(const float4*)src(c + 2, bL, k4s);
        compute(c, ustg[0]);
        if (c + 1 < C)
          *(float4*)(&ustg[1][bbs * 132 + k4s * 4]) = sB;
        __syncthreads();
      }
      if (cc + 1 < C) { // odd chunk c = cc+1 in ustg[1]
        const int c = cc + 1;
        if (c + 2 < C) sB = *(const float4*)src(c + 2, bL, k4s);
        compute(c, ustg[1]);
        if (c + 1 < C)
          *(float4*)(&ustg[0][bbs * 132 + k4s * 4]) = sA;
        __syncthreads();
      }
    }

    // ---- k-split reduction ----
    // stage 1: butterfly over ktlow (lane bits 3/4/5) — in-register
    #pragma unroll
    for (int rr = 0; rr < 4; ++rr)
      #pragma unroll
      for (int i2 = 0; i2 < 4; ++i2) {
        float v = acc[rr][i2];
        v += __shfl_xor(v, 8, 64);
        v += __shfl_xor(v, 16, 64);
        v += __shfl_xor(v, 32, 64);
        acc[rr][i2] = v;
      }
    // stage 2: 4-way over kthigh via small LDS (2048 floats, unions on ustg)
    float* part = &ustg[0][0];
    if ((lane & 56) == 0) {              // ktlow==0 lanes hold the sum
      #pragma unroll
      for (int rr = 0; rr < 4; ++rr)
        #pragma unroll
        for (int i2 = 0; i2 < 4; ++i2)
          part[kh * 512 + (r4 * 4 + rr) * 32 + bg + 8 * i2] = acc[rr][i2];
    }
    __syncthreads();
    if (tid < 512) {
      const int row = tid >> 5;
      float s = part[tid] + part[512 + tid] + part[1024 + tid] +
                part[1536 + tid];
      s += Bv[row >> 2][j0 + (row & 3)];
      gs[tid] = s;
    }
    __syncthreads();
    if (tid < 128) {
      const int jl = tid >> 5, bb = tid & 31;
      const int b = bbase + bb;
      const float fg = sigmoidf_(gs[(0 + jl) * 32 + bb]);
      const float ig = sigmoidf_(gs[(4 + jl) * 32 + bb]);
      const float og = sigmoidf_(gs[(8 + jl) * 32 + bb]);
      const float gg = tanhf(gs[(12 + jl) * 32 + bb]);
      cs = fg * cs + ig * gg;
      hout[b * kH + j0 + jl] = og * tanhf(cs);
    }
  };

  // ---------- fused sequence: 1 domain barrier per step ----------
  {
    const float* __restrict__ h0prev = H0buf[1];
    auto srcA = [&](int c, int b, int k4) {
      return (c == 0) ? p.x + (b * kS + 0) * kD + k4 * 4
                      : h0prev + b * kH + (c - 1) * 128 + k4 * 4;
    };
    runPhase(5, srcA, wlds0, 640, p.b0, c0, H0buf[0]);
  }
  sync_group(domSlots, domGen, cgi, 128, leader, rnd); rnd++;

  for (int t = 0; t < kS; ++t) {
    {
      const float* __restrict__ h0cur  = H0buf[t & 1];
      const float* __restrict__ h1prev = H1buf[(t + 1) & 1];
      auto srcB = [&](int c, int b, int k4) {
        return (c < 4) ? h0cur + b * kH + c * 128 + k4 * 4
                       : h1prev + b * kH + (c - 4) * 128 + k4 * 4;
      };
      runPhase(8, srcB, wlds1, 1024, p.b1, c1, H1buf[t & 1]);
    }
    if (t < kS - 1) {
      const int tn = t + 1;
      const float* __restrict__ h0prev = H0buf[t & 1];
      auto srcA = [&](int c, int b, int k4) {
        return (c == 0) ? p.x + (b * kS + tn) * kD + k4 * 4
                        : h0prev + b * kH + (c - 1) * 128 + k4 * 4;
      };
      runPhase(5, srcA, wlds0, 640, p.b0, c0, H0buf[(t + 1) & 1]);
    }
    sync_group(domSlots, domGen, cgi, 128, leader, rnd); rnd++;
  }

  // ---------- head: fc1 -> (FULL barrier) -> fc2 -> relu ----------
  const float* h1f = H1buf[(kS - 1) & 1];
  if (tid < 128) {
    const int jl = tid >> 5, bb = tid & 31;
    const int b = bbase + bb;
    const float* __restrict__ wrr = p.fc1w + (j0 + jl) * kH;
    const float* __restrict__ hr = h1f + b * kH;
    float s = p.fc1b[j0 + jl];
    for (int k = 0; k < kH; k += 4) {
      const float4 wv = *(const float4*)(wrr + k);
      const float4 hv = *(const float4*)(hr + k);
      s = fmaf(wv.x, hv.x, s); s = fmaf(wv.y, hv.y, s);
      s = fmaf(wv.z, hv.z, s); s = fmaf(wv.w, hv.w, s);
    }
    p.tmp1[b * kH + j0 + jl] = s;
  }
  // fc2 reads tmp1 across BOTH domains -> one full-grid barrier
  sync_group(p.bar + 4224, p.bar + 8320, bid, 256, bid == 0, 0u);

  if (bid < kOut && tid < kB) {
    const int b = tid;
    const float* __restrict__ wrr = p.fc2w + bid * kH;
    const float* __restrict__ tr = p.tmp1 + b * kH;
    float s = p.fc2b[bid];
    for (int k = 0; k < kH; k += 4) {
      const float4 wv = *(const float4*)(wrr + k);
      const float4 tv = *(const float4*)(tr + k);
      s = fmaf(wv.x, tv.x, s); s = fmaf(wv.y, tv.y, s);
      s = fmaf(wv.z, tv.z, s); s = fmaf(wv.w, tv.w, s);
    }
    p.out[b * kOut + bid] = fmaxf(s, 0.f);
  }
}

extern "C" void kernel_launch(void* const* d_in, const int* in_sizes, int n_in,
                              void* d_out, int out_size, void* d_ws, size_t ws_size,
                              hipStream_t stream) {
  (void)in_sizes; (void)n_in; (void)out_size; (void)ws_size;
  Params p;
  p.x = (const float*)d_in[0];
  p.w0[0] = (const float*)d_in[1];  p.b0[0] = (const float*)d_in[2];
  p.w0[1] = (const float*)d_in[3];  p.b0[1] = (const float*)d_in[4];
  p.w0[2] = (const float*)d_in[5];  p.b0[2] = (const float*)d_in[6];
  p.w0[3] = (const float*)d_in[7];  p.b0[3] = (const float*)d_in[8];
  p.w1[0] = (const float*)d_in[9];  p.b1[0] = (const float*)d_in[10];
  p.w1[1] = (const float*)d_in[11]; p.b1[1] = (const float*)d_in[12];
  p.w1[2] = (const float*)d_in[13]; p.b1[2] = (const float*)d_in[14];
  p.w1[3] = (const float*)d_in[15]; p.b1[3] = (const float*)d_in[16];
  p.fc1w = (const float*)d_in[17];  p.fc1b = (const float*)d_in[18];
  p.fc2w = (const float*)d_in[19];  p.fc2b = (const float*)d_in[20];

  float* ws = (float*)d_ws;
  p.H0   = ws;                       // 2 * 64*512
  p.H1   = ws + 2 * kB * kH;         // 2 * 64*512
  p.tmp1 = ws + 4 * kB * kH;         // 64*512
  p.bar  = (unsigned*)((char*)d_ws + kBarOffBytes);
  p.out  = (float*)d_out;

  // barrier state must start at 0 (ws is poisoned 0xAA before every launch)
  hipMemsetAsync((char*)d_ws + kBarOffBytes, 0, 36864, stream);

  void* args[] = { &p };
  hipLaunchCooperativeKernel(reinterpret_cast<const void*>(&lstm_persistent),
                             dim3(kBlocks), dim3(kThreads), args, 0, stream);
}